// Round 12
// baseline (45.820 us; speedup 1.0000x reference)
//
#include <hip/hip_runtime.h>

#define KMAX 64
#define BB 4
#define LL 4096
#define DD 64
#define TOK (BB * LL)   // 16384 tokens per side
#define QPW 8           // queries per wave
#define NBLK 512        // find blocks; blocks 0..127 also produce codes
#define NCODE_BLK 128
#define MAGIC 0x7E57C0DE

typedef unsigned long long u64;

// Single fused kernel, no grid.sync (R9: 55us) and no second node (R11: ~4us
// of serialization). Producer blocks 0..127 compute all 32768 token codes
// (math VERBATIM from the bitwise-verified codes_kernel — strictly
// sequential d=0..63, do NOT tree-reduce: floor() at bucket edges is
// order-sensitive and reorders flip candidates). Then release-store a MAGIC
// flag. Everyone acquire-spins on the 128 flags, then runs find (QPW=8 body
// verified in R9 phase-B; combined-reject from R10; prefetch from R11).
// Replay safety: codes are bitwise-identical every call, so flag-skip on
// replays >=2 reads identical values (no tearing possible: same-value dword
// stores). Post-poison call sees 0xAA pattern != MAGIC -> spins properly.
__global__ __launch_bounds__(256) void fused_kernel(
        const float* __restrict__ q,
        const float* __restrict__ k,
        const float* __restrict__ W,
        int* __restrict__ codes /* ws: [0,TOK)=q, [TOK,2*TOK)=k */,
        int* __restrict__ flags /* ws: 128 ints */,
        int* __restrict__ out) {
    __shared__ float sW[DD * 4];
    int tid = threadIdx.x;
    int blk = blockIdx.x;

    // ---------------- producer phase: codes ----------------
    if (blk < NCODE_BLK) {
        sW[tid] = W[tid];                    // 256 threads = 256 floats
        __syncthreads();
        int gt = blk * 256 + tid;            // 0..32767, exactly 2*TOK
        const float* src = (gt < TOK) ? q : k;
        int t = gt & (TOK - 1);
        const float4* xp = (const float4*)(src + (size_t)t * DD);
        float4 x[16];
        #pragma unroll
        for (int i = 0; i < 16; ++i) x[i] = xp[i];

        float p0 = 0.f, p1 = 0.f, p2 = 0.f, p3 = 0.f;
        const float4* wrow = (const float4*)sW;
        #pragma unroll
        for (int d = 0; d < DD; ++d) {
            float xv = ((const float*)x)[d];
            float b = (xv > 0.f) ? 1.0f : 0.0f;    // binary_quantize
            float4 w = wrow[d];
            p0 = fmaf(b, w.x, p0);
            p1 = fmaf(b, w.y, p1);
            p2 = fmaf(b, w.z, p2);
            p3 = fmaf(b, w.w, p3);
        }
        int h0 = ((int)floorf(p0 * 0.5f)) & 31;    // floor(p/2) mod 32
        int h1 = ((int)floorf(p1 * 0.5f)) & 31;
        int h2 = ((int)floorf(p2 * 0.5f)) & 31;
        int h3 = ((int)floorf(p3 * 0.5f)) & 31;
        codes[gt] = h0 | (h1 << 5) | (h2 << 10) | (h3 << 15);

        __threadfence();                     // make this thread's store device-visible
        __syncthreads();
        if (tid == 0)
            __hip_atomic_store(&flags[blk], MAGIC, __ATOMIC_RELEASE,
                               __HIP_MEMORY_SCOPE_AGENT);
    }

    // ---------------- handshake: wait for all 128 producer flags ----------------
    if (tid < NCODE_BLK) {
        while (__hip_atomic_load(&flags[tid], __ATOMIC_ACQUIRE,
                                 __HIP_MEMORY_SCOPE_AGENT) != MAGIC)
            __builtin_amdgcn_s_sleep(4);
    }
    __syncthreads();

    // ---------------- find phase ----------------
    int lane = tid & 63;
    int wave = blk * 4 + (tid >> 6);         // 0..2047
    int qbase = wave * QPW;                  // 8 queries, never crosses a batch
    int b = qbase >> 12;
    const int4* kc4 = (const int4*)(codes + TOK + b * LL);
    const int* qp = codes + qbase;
    int* outb = out + (size_t)qbase * KMAX;
    u64 lowmask = (1ull << lane) - 1ull;

    int4 kv[16];                             // whole batch in registers
    #pragma unroll
    for (int g = 0; g < 16; ++g) kv[g] = kc4[g * 64 + lane];

    int qc[QPW], cnt[QPW];
    #pragma unroll
    for (int i = 0; i < QPW; ++i) { qc[i] = qp[i]; cnt[i] = 0; }

    #pragma unroll
    for (int g = 0; g < 16; ++g) {           // 16 groups of 256 j
        bool any = false;
        #pragma unroll
        for (int i = 0; i < QPW; ++i)
            any |= (kv[g].x == qc[i]) | (kv[g].y == qc[i]) |
                   (kv[g].z == qc[i]) | (kv[g].w == qc[i]);
        if (__ballot(any) == 0) continue;    // usual case: 1 ballot/group
        int j0 = g * 256 + lane * 4;
        #pragma unroll
        for (int i = 0; i < QPW; ++i) {      // full unroll: no runtime idx
            if (cnt[i] >= KMAX) continue;    // wave-uniform (ballot-derived)
            bool m0 = (kv[g].x == qc[i]), m1 = (kv[g].y == qc[i]);
            bool m2 = (kv[g].z == qc[i]), m3 = (kv[g].w == qc[i]);
            if (__ballot(m0 | m1 | m2 | m3) == 0) continue;
            u64 b0 = __ballot(m0), b1 = __ballot(m1);
            u64 b2 = __ballot(m2), b3 = __ballot(m3);
            int before = __popcll(b0 & lowmask) + __popcll(b1 & lowmask)
                       + __popcll(b2 & lowmask) + __popcll(b3 & lowmask);
            int pos = cnt[i] + before;
            int* op = outb + i * KMAX;
            if (m0) { if (pos < KMAX) op[pos] = j0;     ++pos; }
            if (m1) { if (pos < KMAX) op[pos] = j0 + 1; ++pos; }
            if (m2) { if (pos < KMAX) op[pos] = j0 + 2; ++pos; }
            if (m3) { if (pos < KMAX) op[pos] = j0 + 3; ++pos; }
            cnt[i] += __popcll(b0) + __popcll(b1) + __popcll(b2) + __popcll(b3);
        }
    }
    #pragma unroll
    for (int i = 0; i < QPW; ++i) {          // -1 tail fill, coalesced
        int p = cnt[i] + lane;
        if (p < KMAX) outb[i * KMAX + p] = -1;
    }
}

extern "C" void kernel_launch(void* const* d_in, const int* in_sizes, int n_in,
                              void* d_out, int out_size, void* d_ws, size_t ws_size,
                              hipStream_t stream) {
    const float* q = (const float*)d_in[0];
    const float* k = (const float*)d_in[1];
    const float* W = (const float*)d_in[2];
    int* out = (int*)d_out;
    int* codes = (int*)d_ws;                           // 2*TOK ints (128 KB)
    int* flags = (int*)((char*)d_ws + 2 * TOK * 4);    // 128 ints

    fused_kernel<<<NBLK, 256, 0, stream>>>(q, k, W, codes, flags, out);
}

// Round 13
// 23.170 us; speedup vs baseline: 1.9775x; 1.9775x over previous
//
#include <hip/hip_runtime.h>

#define KMAX 64
#define BB 4
#define LL 4096
#define DD 64
#define TOK (BB * LL)   // 16384 tokens per side
#define QPW 4           // queries per wave

typedef unsigned long long u64;

// Kernel 1: k-codes ONLY (q-codes moved into find). One thread per key token.
// Math VERBATIM from the bitwise-verified codes_kernel (absmax 0.0 since R1):
// strictly sequential d=0..63 fmaf accumulation — DO NOT tree-reduce
// (floor() at bucket edges is order-sensitive). 256 blocks x 64 thr = 1/CU.
__global__ __launch_bounds__(64) void kcodes_kernel(
        const float* __restrict__ k,
        const float* __restrict__ W,
        int* __restrict__ kcodes /* [TOK] */) {
    __shared__ float sW[DD * 4];
    int lane = threadIdx.x;
    #pragma unroll
    for (int i = 0; i < 4; ++i) sW[i * 64 + lane] = W[i * 64 + lane];
    __syncthreads();

    int t = blockIdx.x * 64 + lane;          // grid covers TOK exactly
    const float4* xp = (const float4*)(k + (size_t)t * DD);
    float4 x[16];
    #pragma unroll
    for (int i = 0; i < 16; ++i) x[i] = xp[i];

    float p0 = 0.f, p1 = 0.f, p2 = 0.f, p3 = 0.f;
    const float4* wrow = (const float4*)sW;
    #pragma unroll
    for (int d = 0; d < DD; ++d) {
        float xv = ((const float*)x)[d];
        float b = (xv > 0.f) ? 1.0f : 0.0f;      // binary_quantize
        float4 w = wrow[d];
        p0 = fmaf(b, w.x, p0);
        p1 = fmaf(b, w.y, p1);
        p2 = fmaf(b, w.z, p2);
        p3 = fmaf(b, w.w, p3);
    }
    int h0 = ((int)floorf(p0 * 0.5f)) & 31;      // floor(p/2) mod 32
    int h1 = ((int)floorf(p1 * 0.5f)) & 31;
    int h2 = ((int)floorf(p2 * 0.5f)) & 31;
    int h3 = ((int)floorf(p3 * 0.5f)) & 31;
    kcodes[t] = h0 | (h1 << 5) | (h2 << 10) | (h3 << 15);
}

// Kernel 2: 4096 waves, 4 queries per wave. Computes its OWN q-codes inline
// (lane-redundant: lanes 16i..16i+15 all run the bitwise-identical fmaf
// chain for query qbase+i — same d=0..63 order, same fmaf, same floor/mask;
// then __shfl from lane 16i). Scan body VERBATIM from R11 (absmax 0.0):
// whole-batch register prefetch, combined 1-ballot reject, lane-major
// ordered write (j = g*256 + lane*4 + e; before = sum of 4 ballots &
// lowmask; within-lane order via sequential pos++), -1 tail fill.
__global__ __launch_bounds__(256) void find_kernel(
        const float* __restrict__ q,
        const float* __restrict__ W,
        const int* __restrict__ kcodes,
        int* __restrict__ out) {
    __shared__ float sW[DD * 4];
    int tid = threadIdx.x;
    sW[tid] = W[tid];                        // 256 threads = 256 floats
    __syncthreads();

    int gtid = blockIdx.x * 256 + tid;
    int wave = gtid >> 6;                    // 0..4095
    int lane = gtid & 63;
    int qbase = wave * QPW;                  // 4 queries, never crosses a batch
    int b = qbase >> 12;

    // ---- inline q-code (lane-redundant, bitwise-identical math) ----
    {
        int myq = qbase + (lane >> 4);       // this lane's query token
        const float4* xp = (const float4*)(q + (size_t)myq * DD);
        float4 x[16];
        #pragma unroll
        for (int i = 0; i < 16; ++i) x[i] = xp[i];
        float p0 = 0.f, p1 = 0.f, p2 = 0.f, p3 = 0.f;
        const float4* wrow = (const float4*)sW;
        #pragma unroll
        for (int d = 0; d < DD; ++d) {
            float xv = ((const float*)x)[d];
            float bq = (xv > 0.f) ? 1.0f : 0.0f;
            float4 w = wrow[d];
            p0 = fmaf(bq, w.x, p0);
            p1 = fmaf(bq, w.y, p1);
            p2 = fmaf(bq, w.z, p2);
            p3 = fmaf(bq, w.w, p3);
        }
        int h0 = ((int)floorf(p0 * 0.5f)) & 31;
        int h1 = ((int)floorf(p1 * 0.5f)) & 31;
        int h2 = ((int)floorf(p2 * 0.5f)) & 31;
        int h3 = ((int)floorf(p3 * 0.5f)) & 31;
        int mycode = h0 | (h1 << 5) | (h2 << 10) | (h3 << 15);
        // distribute: query i's code lives in lanes 16i..16i+15
        // (written into qc[] below via shfl)
        int c0 = __shfl(mycode, 0, 64);
        int c1 = __shfl(mycode, 16, 64);
        int c2 = __shfl(mycode, 32, 64);
        int c3 = __shfl(mycode, 48, 64);
        // stash in a small array for the unrolled scan
        // (compile-time indexed everywhere below)
        int qc_[QPW] = {c0, c1, c2, c3};
        int cnt_[QPW] = {0, 0, 0, 0};

        const int4* kc4 = (const int4*)(kcodes + b * LL);
        int* outb = out + (size_t)qbase * KMAX;
        u64 lowmask = (1ull << lane) - 1ull;

        // ---- whole-batch register prefetch (R11) ----
        int4 kv[16];
        #pragma unroll
        for (int g = 0; g < 16; ++g) kv[g] = kc4[g * 64 + lane];

        #pragma unroll
        for (int g = 0; g < 16; ++g) {                 // 16 groups of 256 j
            bool any = false;
            #pragma unroll
            for (int i = 0; i < QPW; ++i)
                any |= (kv[g].x == qc_[i]) | (kv[g].y == qc_[i]) |
                       (kv[g].z == qc_[i]) | (kv[g].w == qc_[i]);
            if (__ballot(any) == 0) continue;          // usual case
            int j0 = g * 256 + lane * 4;
            #pragma unroll
            for (int i = 0; i < QPW; ++i) {            // full unroll
                if (cnt_[i] >= KMAX) continue;         // wave-uniform
                bool m0 = (kv[g].x == qc_[i]), m1 = (kv[g].y == qc_[i]);
                bool m2 = (kv[g].z == qc_[i]), m3 = (kv[g].w == qc_[i]);
                if (__ballot(m0 | m1 | m2 | m3) == 0) continue;
                u64 b0 = __ballot(m0), b1 = __ballot(m1);
                u64 b2 = __ballot(m2), b3 = __ballot(m3);
                int before = __popcll(b0 & lowmask) + __popcll(b1 & lowmask)
                           + __popcll(b2 & lowmask) + __popcll(b3 & lowmask);
                int pos = cnt_[i] + before;
                int* op = outb + i * KMAX;
                if (m0) { if (pos < KMAX) op[pos] = j0;     ++pos; }
                if (m1) { if (pos < KMAX) op[pos] = j0 + 1; ++pos; }
                if (m2) { if (pos < KMAX) op[pos] = j0 + 2; ++pos; }
                if (m3) { if (pos < KMAX) op[pos] = j0 + 3; ++pos; }
                cnt_[i] += __popcll(b0) + __popcll(b1) + __popcll(b2) + __popcll(b3);
            }
        }
        #pragma unroll
        for (int i = 0; i < QPW; ++i) {                // -1 tail fill
            int p = cnt_[i] + lane;
            if (p < KMAX) outb[i * KMAX + p] = -1;
        }
    }
}

extern "C" void kernel_launch(void* const* d_in, const int* in_sizes, int n_in,
                              void* d_out, int out_size, void* d_ws, size_t ws_size,
                              hipStream_t stream) {
    const float* q = (const float*)d_in[0];
    const float* k = (const float*)d_in[1];
    const float* W = (const float*)d_in[2];
    int* out = (int*)d_out;
    int* kcodes = (int*)d_ws;                // TOK ints (64 KB)

    kcodes_kernel<<<TOK / 64, 64, 0, stream>>>(k, W, kcodes);

    const int total_threads = (TOK / QPW) * 64;    // 4096 waves
    find_kernel<<<total_threads / 256, 256, 0, stream>>>(q, W, kcodes, out);
}

// Round 14
// 20.349 us; speedup vs baseline: 2.2517x; 1.1386x over previous
//
#include <hip/hip_runtime.h>

#define KMAX 64
#define BB 4
#define LL 4096
#define DD 64
#define TOK (BB * LL)   // 16384 tokens per side
#define QPW 4           // queries per wave

typedef unsigned long long u64;

// Phase 1 (math VERBATIM, bitwise-verified absmax 0.0 since R1): one thread
// per token-side; strictly sequential d=0..63 fmaf accumulation — DO NOT
// tree-reduce (floor() at bucket edges is order-sensitive).
// 512 blocks x 64 threads -> all 256 CUs engaged (R10 config).
__global__ __launch_bounds__(64) void codes_kernel(
        const float* __restrict__ q,
        const float* __restrict__ k,
        const float* __restrict__ W,
        int* __restrict__ codes /* [0,TOK)=qcodes, [TOK,2*TOK)=kcodes */) {
    __shared__ float sW[DD * 4];
    int lane = threadIdx.x;
    #pragma unroll
    for (int i = 0; i < 4; ++i) sW[i * 64 + lane] = W[i * 64 + lane];
    __syncthreads();

    int u = blockIdx.x * 64 + lane;          // grid covers 2*TOK exactly
    const float* src = (u < TOK) ? q : k;
    int t = u & (TOK - 1);

    const float4* xp = (const float4*)(src + (size_t)t * DD);
    float4 x[16];
    #pragma unroll
    for (int i = 0; i < 16; ++i) x[i] = xp[i];

    float p0 = 0.f, p1 = 0.f, p2 = 0.f, p3 = 0.f;
    const float4* wrow = (const float4*)sW;
    #pragma unroll
    for (int d = 0; d < DD; ++d) {
        float xv = ((const float*)x)[d];
        float b = (xv > 0.f) ? 1.0f : 0.0f;      // binary_quantize
        float4 w = wrow[d];
        p0 = fmaf(b, w.x, p0);
        p1 = fmaf(b, w.y, p1);
        p2 = fmaf(b, w.z, p2);
        p3 = fmaf(b, w.w, p3);
    }
    int h0 = ((int)floorf(p0 * 0.5f)) & 31;      // floor(p/2) mod 32
    int h1 = ((int)floorf(p1 * 0.5f)) & 31;
    int h2 = ((int)floorf(p2 * 0.5f)) & 31;
    int h3 = ((int)floorf(p3 * 0.5f)) & 31;
    codes[u] = h0 | (h1 << 5) | (h2 << 10) | (h3 << 15);
}

// Phase 2: 1024 blocks x 4 waves, 4 queries per wave (16/block). The block
// stages its batch's 4096 k-codes (16 KB) in LDS ONCE -> global kcodes
// traffic drops 67 MB -> 16 MB (the R13 post-mortem's L3-traffic diagnosis).
// Each wave then register-prefetches its 16 int4 from LDS and runs the
// R11-VERBATIM scan body (absmax 0.0): combined 1-ballot reject, lane-major
// ordered write (j = g*256 + lane*4 + e; before = sum of 4 ballots &
// lowmask; within-lane order via sequential pos++), -1 tail fill.
__global__ __launch_bounds__(256) void find_kernel(
        const int* __restrict__ qcodes,
        const int* __restrict__ kcodes,
        int* __restrict__ out) {
    __shared__ int skc[LL];                  // 16 KB
    int tid = threadIdx.x;
    int blk = blockIdx.x;                    // 1024 blocks
    int b = blk >> 8;                        // 256 blocks per batch

    // stage batch k-codes: 256 threads x 4 int4 = 16 KB, coalesced
    const int4* src = (const int4*)(kcodes + b * LL);
    int4* dst = (int4*)skc;
    #pragma unroll
    for (int i = 0; i < 4; ++i) dst[tid + i * 256] = src[tid + i * 256];
    __syncthreads();

    int wave = blk * 4 + (tid >> 6);         // 0..4095
    int lane = tid & 63;
    int qbase = wave * QPW;                  // 4 queries, never crosses a batch
    const int* qp = qcodes + qbase;
    int* outb = out + (size_t)qbase * KMAX;
    u64 lowmask = (1ull << lane) - 1ull;

    // ---- whole-batch register prefetch, now from LDS ----
    const int4* skc4 = (const int4*)skc;
    int4 kv[16];
    #pragma unroll
    for (int g = 0; g < 16; ++g) kv[g] = skc4[g * 64 + lane];

    int qc[QPW], cnt[QPW];
    #pragma unroll
    for (int i = 0; i < QPW; ++i) { qc[i] = qp[i]; cnt[i] = 0; }

    #pragma unroll
    for (int g = 0; g < 16; ++g) {                 // 16 groups of 256 j
        bool a0 = (kv[g].x == qc[0]) | (kv[g].y == qc[0]) | (kv[g].z == qc[0]) | (kv[g].w == qc[0]);
        bool a1 = (kv[g].x == qc[1]) | (kv[g].y == qc[1]) | (kv[g].z == qc[1]) | (kv[g].w == qc[1]);
        bool a2 = (kv[g].x == qc[2]) | (kv[g].y == qc[2]) | (kv[g].z == qc[2]) | (kv[g].w == qc[2]);
        bool a3 = (kv[g].x == qc[3]) | (kv[g].y == qc[3]) | (kv[g].z == qc[3]) | (kv[g].w == qc[3]);
        if (__ballot(a0 | a1 | a2 | a3) == 0) continue;    // usual case
        int j0 = g * 256 + lane * 4;
        #pragma unroll
        for (int i = 0; i < QPW; ++i) {            // full unroll: no runtime idx
            if (cnt[i] >= KMAX) continue;          // wave-uniform
            bool m0 = (kv[g].x == qc[i]), m1 = (kv[g].y == qc[i]);
            bool m2 = (kv[g].z == qc[i]), m3 = (kv[g].w == qc[i]);
            if (__ballot(m0 | m1 | m2 | m3) == 0) continue;
            u64 b0 = __ballot(m0), b1 = __ballot(m1);
            u64 b2 = __ballot(m2), b3 = __ballot(m3);
            int before = __popcll(b0 & lowmask) + __popcll(b1 & lowmask)
                       + __popcll(b2 & lowmask) + __popcll(b3 & lowmask);
            int pos = cnt[i] + before;
            int* op = outb + i * KMAX;
            if (m0) { if (pos < KMAX) op[pos] = j0;     ++pos; }
            if (m1) { if (pos < KMAX) op[pos] = j0 + 1; ++pos; }
            if (m2) { if (pos < KMAX) op[pos] = j0 + 2; ++pos; }
            if (m3) { if (pos < KMAX) op[pos] = j0 + 3; ++pos; }
            cnt[i] += __popcll(b0) + __popcll(b1) + __popcll(b2) + __popcll(b3);
        }
    }
    #pragma unroll
    for (int i = 0; i < QPW; ++i) {                // -1 tail fill, coalesced
        int p = cnt[i] + lane;
        if (p < KMAX) outb[i * KMAX + p] = -1;
    }
}

extern "C" void kernel_launch(void* const* d_in, const int* in_sizes, int n_in,
                              void* d_out, int out_size, void* d_ws, size_t ws_size,
                              hipStream_t stream) {
    const float* q = (const float*)d_in[0];
    const float* k = (const float*)d_in[1];
    const float* W = (const float*)d_in[2];
    int* out = (int*)d_out;
    int* codes = (int*)d_ws;                 // [2*TOK] ints (128 KB)
    int* qcodes = codes;
    int* kcodes = codes + TOK;

    codes_kernel<<<(2 * TOK) / 64, 64, 0, stream>>>(q, k, W, codes);

    find_kernel<<<TOK / (QPW * 4), 256, 0, stream>>>(qcodes, kcodes, out);
}